// Round 1
// baseline (402.609 us; speedup 1.0000x reference)
//
#include <hip/hip_runtime.h>

// NestedDropout: out[i,j] = X[i,j] if j < clip(geom[i]*8, 8, 512) else 0.
// B = 131072 rows, FEAT_DIM = 512 (float32). Pure memory-bound masked copy.
//
// Key facts exploited:
//  - cutoff is a multiple of GROUP=8, >= 8: a 4-aligned float4 is either
//    fully kept or fully zeroed -> one predicate per float4, no lane masks.
//  - one row = 128 float4 threads = 2 full wave64s -> the cutoff predicate
//    is wave-uniform, so the "skip load past cutoff" branch has no
//    divergence cost and genuinely cuts HBM read traffic (~2x on average).

constexpr int FEAT  = 512;
constexpr int GROUP = 8;
constexpr int VPR   = FEAT / 4;   // float4 vectors per row = 128

__global__ __launch_bounds__(256) void NestedDropout_60430189854823_kernel(
    const float4* __restrict__ X4,
    const int*    __restrict__ geom,
    float4*       __restrict__ out4,
    int total_vec)
{
    int idx = blockIdx.x * blockDim.x + threadIdx.x;
    if (idx >= total_vec) return;

    int row      = idx >> 7;           // idx / 128
    int col_base = (idx & (VPR - 1)) << 2;  // element column of this float4

    int cutoff = geom[row] * GROUP;
    cutoff = cutoff < GROUP ? GROUP : cutoff;
    cutoff = cutoff > FEAT  ? FEAT  : cutoff;

    float4 v = make_float4(0.0f, 0.0f, 0.0f, 0.0f);
    if (col_base < cutoff) {
        v = X4[idx];                   // skipped entirely past cutoff -> less HBM read
    }
    out4[idx] = v;
}

extern "C" void kernel_launch(void* const* d_in, const int* in_sizes, int n_in,
                              void* d_out, int out_size, void* d_ws, size_t ws_size,
                              hipStream_t stream) {
    const float4* X4   = (const float4*)d_in[0];   // [B, 512] float32
    const int*    geom = (const int*)d_in[1];      // [B] int32
    float4*       out4 = (float4*)d_out;           // [B, 512] float32

    int total_vec = in_sizes[0] / 4;               // B * 128
    int block = 256;
    int grid  = (total_vec + block - 1) / block;

    NestedDropout_60430189854823_kernel<<<grid, block, 0, stream>>>(
        X4, geom, out4, total_vec);
}

// Round 3
// 393.114 us; speedup vs baseline: 1.0242x; 1.0242x over previous
//
#include <hip/hip_runtime.h>

// NestedDropout: out[i,j] = X[i,j] if j < clip(geom[i]*8, 8, 512) else 0.
// B = 131072 rows, FEAT_DIM = 512 float32. Memory-bound masked copy.
//
// Structure: one wave64 per row. 128 float4/row = 2 vectors per lane.
//  - cutoff is wave-uniform -> readfirstlane forces an s_load_dword (SMEM)
//    instead of a 64-lane VMEM broadcast, shortening the dependent chain.
//  - two independent predicated loads + two stores per lane -> 2x MLP.
//  - nontemporal on the streaming X/out traffic (each byte touched once,
//    385 MB >> 32 MB L2) to avoid L2 pollution. Uses clang ext_vector_type
//    (HIP_vector_type structs are rejected by the nontemporal builtins).
//  - loads past cutoff are skipped entirely -> ~2x less HBM read on average.

typedef float v4f __attribute__((ext_vector_type(4)));

constexpr int FEAT  = 512;
constexpr int GROUP = 8;
constexpr int VPR   = FEAT / 4;   // float4 vectors per row = 128

__global__ __launch_bounds__(256) void NestedDropout_60430189854823_kernel(
    const v4f* __restrict__ X4,
    const int* __restrict__ geom,
    v4f*       __restrict__ out4,
    int nrows)
{
    int wave = blockIdx.x * 4 + (threadIdx.x >> 6);   // 4 waves per block
    int lane = threadIdx.x & 63;
    if (wave >= nrows) return;

    int row = __builtin_amdgcn_readfirstlane(wave);   // wave-uniform -> SGPR

    int cutoff = geom[row] * GROUP;                   // s_load_dword
    cutoff = cutoff < GROUP ? GROUP : cutoff;
    cutoff = cutoff > FEAT  ? FEAT  : cutoff;
    int cvec = cutoff >> 2;                           // float4s kept (>= 2)

    const v4f* xrow = X4   + (size_t)row * VPR;
    v4f*       orow = out4 + (size_t)row * VPR;

    v4f a = (v4f)(0.0f);
    v4f b = (v4f)(0.0f);

    // two independent predicated loads -> both in flight simultaneously
    if (lane < cvec)      a = __builtin_nontemporal_load(&xrow[lane]);
    if (lane + 64 < cvec) b = __builtin_nontemporal_load(&xrow[lane + 64]);

    __builtin_nontemporal_store(a, &orow[lane]);
    __builtin_nontemporal_store(b, &orow[lane + 64]);
}

extern "C" void kernel_launch(void* const* d_in, const int* in_sizes, int n_in,
                              void* d_out, int out_size, void* d_ws, size_t ws_size,
                              hipStream_t stream) {
    const v4f* X4   = (const v4f*)d_in[0];   // [B, 512] float32
    const int* geom = (const int*)d_in[1];   // [B] int32
    v4f*       out4 = (v4f*)d_out;           // [B, 512] float32

    int nrows = in_sizes[0] / FEAT;          // B = 131072
    int block = 256;                         // 4 waves = 4 rows/block
    int grid  = (nrows + 3) / 4;

    NestedDropout_60430189854823_kernel<<<grid, block, 0, stream>>>(
        X4, geom, out4, nrows);
}